// Round 8
// baseline (406.688 us; speedup 1.0000x reference)
//
#include <hip/hip_runtime.h>
#include <hip/hip_bf16.h>

// IrrepLinear: out[b, o*25+m] = sum_i x[b, i*25+m] * W[l(m), o, i]  (+bias at m=0)
// r8 = r7 skeleton (16b x 64o x 25m blocks, 4 waves, sibling-coresident XCD map,
// LDS epilogue) with staging flipped from 52 scalar loads + b64 writes to
// 13 float4 loads + 52 b16 scatter-writes. Rationale: r2/r5/r7 triangulate a
// serial-sum pipe model where 832 scalar loads/thread (~177us of TA issue) was
// r7's dominant term; float4 cuts it 4x. Scatter pitch 46 ushorts = 23 words,
// 23 coprime 32 -> all 25 m rows on distinct banks (writes ~2/bank = free);
// A-frag b128 read starts (-lr+4lh) mod 32 -> uniform 8/bank = b128 floor.

typedef __bf16 bf16x8v __attribute__((ext_vector_type(8)));
typedef float floatx4 __attribute__((ext_vector_type(4)));
typedef unsigned short ushort_t;
typedef unsigned short ushortx4 __attribute__((ext_vector_type(4)));

#define ROW_F 12800          // floats per batch row (512*25)
#define PITCH 46             // ushorts per LDS row: 32 k-data + 14 pad (92B)
#define LDS_USH (400 * 46)   // 36800 B

__device__ __forceinline__ ushort_t f2bf(float f) {
    __hip_bfloat16 h = __float2bfloat16(f);   // RNE
    return __builtin_bit_cast(ushort_t, h);
}

// weight fp32 [5][512][512] -> bf16 in ws (same layout, k contiguous)
__global__ void cvt_w_kernel(const float* __restrict__ w, ushort_t* __restrict__ wb) {
    int i = (blockIdx.x * 256 + threadIdx.x) * 4;   // 1310720 elems, 1280x256 exact
    floatx4 v = *reinterpret_cast<const floatx4*>(w + i);
    ushortx4 h;
    h.x = f2bf(v[0]); h.y = f2bf(v[1]); h.z = f2bf(v[2]); h.w = f2bf(v[3]);
    *reinterpret_cast<ushortx4*>(wb + i) = h;
}

__global__ __launch_bounds__(256) void irrep_kernel(
        const float* __restrict__ x, const ushort_t* __restrict__ wb,
        const float* __restrict__ bias, float* __restrict__ out) {
    __shared__ __align__(16) ushort_t Asm[LDS_USH];

    const int tid = threadIdx.x, lane = tid & 63;
    const int wv = tid >> 6;                  // 4 waves = 4 o-slices of 16
    const int lr = lane & 15, lh = lane >> 4;

    // Sibling-coresident same-XCD mapping (proven r7: FETCH 173MB): all 8
    // o-siblings of a btile share bid%8 (one XCD) within a 64-bid window.
    const int bid   = blockIdx.x;             // 2048 blocks
    const int osib  = (bid >> 3) & 7;
    const int btile = (bid & 7) | ((bid >> 6) << 3);
    const int b0 = btile * 16, o0 = osib * 64, ow = o0 + wv * 16;

    constexpr int LOF[25] = {0,1,1,1,2,2,2,2,2,3,3,3,3,3,3,3,4,4,4,4,4,4,4,4,4};

    // ---- staging: step s covers floats [s*800, s*800+800) per b-row
    // (= k in [32s,32s+32) x all 25 m, contiguous since addr = i*25+m).
    // Thread's quad Q = bb*200 + q: float4 at bb-row offset q*16B; elements
    // (4q+u): m=(4q+u)%25, k=(4q+u)/25 (step-invariant!).
    int goffB[13], w0[13], m0a[13];
#pragma unroll
    for (int it = 0; it < 13; ++it) {
        int Q = tid + 256 * it;
        if (Q < 3200) {
            int bb = Q / 200, q = Q - bb * 200;
            int e0 = 4 * q;
            int k0 = e0 / 25, m0 = e0 - k0 * 25;
            goffB[it] = bb * 51200 + q * 16;          // bytes within step-slab
            w0[it]    = (bb * 25 + m0) * PITCH + k0;  // ushort index
            m0a[it]   = m0;
        } else { goffB[it] = 0; w0[it] = 0; m0a[it] = 30; }  // m0a>24: never wraps twice
    }

    floatx4 vbuf[13];
    const char* xb = (const char*)x + (size_t)b0 * 51200;
    auto issue = [&](int s) {     // 13 coalesced float4 loads for step s
        const char* base = xb + s * 3200;
#pragma unroll
        for (int it = 0; it < 13; ++it) if (tid + 256 * it < 3200)
            vbuf[it] = *reinterpret_cast<const floatx4*>(base + goffB[it]);
    };
    auto scat = [&]() {           // 52 b16 writes, banks spread by 23m mod 32
#pragma unroll
        for (int it = 0; it < 13; ++it) if (tid + 256 * it < 3200) {
#pragma unroll
            for (int u = 0; u < 4; ++u) {
                int a = w0[it] + u * PITCH;
                if (m0a[it] + u >= 25) a -= (25 * PITCH - 1);  // m-=25, k+=1
                Asm[a] = f2bf(vbuf[it][u]);
            }
        }
    };

    floatx4 acc[25];
#pragma unroll
    for (int m = 0; m < 25; ++m) acc[m] = (floatx4){0.f, 0.f, 0.f, 0.f};

    issue(0);                     // stage step 0
#pragma unroll 1
    for (int s = 0; s < 16; ++s) {
        __syncthreads();          // previous step's A-reads done
        scat();                   // waits on vbuf vmcnt
        __syncthreads();          // tile visible
        if (s < 15) issue(s + 1); // next step's loads in flight under compute

        bf16x8v bfr[5];           // 5 l-deduped B-frags from L2
#pragma unroll
        for (int l = 0; l < 5; ++l)
            bfr[l] = *reinterpret_cast<const bf16x8v*>(
                wb + (size_t)(l * 512 + ow + lr) * 512 + s * 32 + lh * 8);
#pragma unroll
        for (int m = 0; m < 25; ++m) {
            const bf16x8v a = *reinterpret_cast<const bf16x8v*>(
                &Asm[(lr * 25 + m) * PITCH + lh * 8]);
            acc[m] = __builtin_amdgcn_mfma_f32_16x16x32_bf16(a, bfr[LOF[m]], acc[m], 0, 0, 0);
        }
    }

    // bias on the m=0 component only
    {
        float bv = bias[ow + lr];
#pragma unroll
        for (int r = 0; r < 4; ++r) acc[0][r] += bv;
    }

    // ---- LDS-staged epilogue: 4 passes x 4 b-rows; global stores = contiguous
    // 6.4KB float4 runs (keeps WRITE_SIZE at exactly 204.8MB).
    float* ep = reinterpret_cast<float*>(Asm);
    constexpr int EPROW = 1608;   // 1600 + 8 pad
#pragma unroll 1
    for (int p = 0; p < 4; ++p) {
        __syncthreads();          // k-loop reads / prior pass reads done
        if (lh == p) {            // D rows = lh*4 + r -> rows 4p..4p+3
#pragma unroll
            for (int m = 0; m < 25; ++m) {
                int cb = (wv * 16 + lr) * 25 + m;
#pragma unroll
                for (int r = 0; r < 4; ++r) ep[r * EPROW + cb] = acc[m][r];
            }
        }
        __syncthreads();
#pragma unroll 1
        for (int idx = tid; idx < 1600; idx += 256) {
            int rr = idx / 400, c4 = idx - rr * 400;
            floatx4 v = *reinterpret_cast<const floatx4*>(ep + rr * EPROW + c4 * 4);
            *reinterpret_cast<floatx4*>(
                out + (size_t)(b0 + p * 4 + rr) * ROW_F + o0 * 25 + c4 * 4) = v;
        }
    }
}

extern "C" void kernel_launch(void* const* d_in, const int* in_sizes, int n_in,
                              void* d_out, int out_size, void* d_ws, size_t ws_size,
                              hipStream_t stream) {
    const float* x    = (const float*)d_in[0];
    const float* w    = (const float*)d_in[1];
    const float* bias = (const float*)d_in[2];
    float* outp       = (float*)d_out;
    ushort_t* wb      = (ushort_t*)d_ws;    // 2.62 MB bf16 weights

    cvt_w_kernel<<<1280, 256, 0, stream>>>(w, wb);
    irrep_kernel<<<2048, 256, 0, stream>>>(x, wb, bias, outp);
}

// Round 9
// 325.089 us; speedup vs baseline: 1.2510x; 1.2510x over previous
//
#include <hip/hip_runtime.h>
#include <hip/hip_bf16.h>

// IrrepLinear: out[b, o*25+m] = sum_i x[b, i*25+m] * W[l(m), o, i]  (+bias at m=0)
// r9: attack A-read amplification. Block = 16b x 128o x 25m, 8 waves =
// 2 m-halves (13/12 m; l-dedup intact: {0..3} / {3,4}) x 4 o-quads, OF=2
// (each A-frag feeds 2 MFMAs). 1024 blocks -> x staged 4x not 8x. Total LDS
// reads 3.3GB -> 1.65GB, writes 0.84 -> 0.42GB, staging loads halved.
// Proven pieces kept: r7 quad staging (pitch 44), sibling-coresident XCD map,
// LDS epilogue (WRITE 204.8MB exact).

typedef __bf16 bf16x8v __attribute__((ext_vector_type(8)));
typedef float floatx4 __attribute__((ext_vector_type(4)));
typedef unsigned short ushort_t;
typedef unsigned short ushortx4 __attribute__((ext_vector_type(4)));

#define ROW_F 12800          // floats per batch row (512*25)
#define PITCH 44             // ushorts per LDS A row (88B): 22 words, gcd(22,32)=2
#define SMEM_BYTES 51392     // max(staging 35200, epilogue 4*3208*4=51328) +pad

__device__ __forceinline__ ushort_t f2bf(float f) {
    __hip_bfloat16 h = __float2bfloat16(f);   // RNE
    return __builtin_bit_cast(ushort_t, h);
}

// weight fp32 [5][512][512] -> bf16 in ws (same layout, k contiguous)
__global__ void cvt_w_kernel(const float* __restrict__ w, ushort_t* __restrict__ wb) {
    int i = (blockIdx.x * 256 + threadIdx.x) * 4;   // 1310720 elems, 1280x256 exact
    floatx4 v = *reinterpret_cast<const floatx4*>(w + i);
    ushortx4 h;
    h.x = f2bf(v[0]); h.y = f2bf(v[1]); h.z = f2bf(v[2]); h.w = f2bf(v[3]);
    *reinterpret_cast<ushortx4*>(wb + i) = h;
}

__global__ __launch_bounds__(512, 2) void irrep_kernel(
        const float* __restrict__ x, const ushort_t* __restrict__ wb,
        const float* __restrict__ bias, float* __restrict__ out) {
    __shared__ __align__(16) unsigned char smem[SMEM_BYTES];
    ushort_t* Asm = reinterpret_cast<ushort_t*>(smem);

    const int tid = threadIdx.x, lane = tid & 63;
    const int wv = tid >> 6;                  // 8 waves
    const int lr = lane & 15, lh = lane >> 4;
    const int mh = wv >> 2;                   // m-half: 0 -> m 0..12, 1 -> m 13..24
    const int oq = wv & 3;                    // o-quad of 32 cols

    // Sibling-coresident same-XCD mapping: 4 o-siblings (o128) of a btile share
    // bid%8 (one XCD) within a 32-bid window -> x window fetched once.
    const int bid   = blockIdx.x;             // 1024 blocks
    const int osib  = (bid >> 3) & 3;
    const int btile = (bid & 7) | ((bid >> 5) << 3);
    const int b0 = btile * 16, o0 = osib * 128;
    const int ob = o0 + oq * 32;              // wave cols: ob + of*16 + lr

    // ---- staging quads: Q = bb*200 + kq*25 + m (m fastest). 3200 quads/step,
    // 512 threads -> 6 full iters + (tid<128) a 7th.
    int goff[7], woff[7];
#pragma unroll
    for (int i = 0; i < 7; ++i) {
        int Q = tid + 512 * i;
        if (Q < 3200) {
            int bb = Q / 200, r = Q - bb * 200;
            int kq = r / 25, m = r - kq * 25;
            goff[i] = bb * ROW_F + kq * 100 + m;          // float units
            woff[i] = (bb * 25 + m) * PITCH + kq * 4;     // ushort units
        } else { goff[i] = 0; woff[i] = 0; }
    }
    const float* xb = x + (size_t)b0 * ROW_F;

    float vbuf[7][4];
    auto issue = [&]() {          // next step's x -> regs (overlaps compute)
#pragma unroll
        for (int i = 0; i < 7; ++i) if (tid + 512 * i < 3200) {
            const float* p = xb + goff[i];
#pragma unroll
            for (int j = 0; j < 4; ++j) vbuf[i][j] = p[j * 25];
            goff[i] += 800;       // advance one K32-step (32*25 floats)
        }
    };
    auto scat = [&]() {           // 7 x ds_write_b64
#pragma unroll
        for (int i = 0; i < 7; ++i) if (tid + 512 * i < 3200) {
            ushortx4 h;
#pragma unroll
            for (int j = 0; j < 4; ++j) h[j] = f2bf(vbuf[i][j]);
            *reinterpret_cast<ushortx4*>(&Asm[woff[i]]) = h;
        }
    };

    floatx4 acc[13][2];           // [mm][of]; mh=1 uses mm 0..11
#pragma unroll
    for (int mm = 0; mm < 13; ++mm)
#pragma unroll
        for (int of = 0; of < 2; ++of) acc[mm][of] = (floatx4){0.f, 0.f, 0.f, 0.f};

    issue();                      // stage step 0
#pragma unroll 1
    for (int s = 0; s < 16; ++s) {
        __syncthreads();          // previous step's A-reads done
        scat();                   // waits on vbuf vmcnt
        __syncthreads();          // tile visible
        if (s < 15) issue();      // next step's loads in flight under compute

        if (mh == 0) {            // m 0..12, l in {0,1,2,3}
            bf16x8v bfr[4][2];
#pragma unroll
            for (int l = 0; l < 4; ++l)
#pragma unroll
                for (int of = 0; of < 2; ++of)
                    bfr[l][of] = *reinterpret_cast<const bf16x8v*>(
                        wb + (size_t)(l * 512 + ob + of * 16 + lr) * 512 + s * 32 + lh * 8);
            constexpr int L0[13] = {0,1,1,1,2,2,2,2,2,3,3,3,3};
#pragma unroll
            for (int mm = 0; mm < 13; ++mm) {
                const bf16x8v a = *reinterpret_cast<const bf16x8v*>(
                    &Asm[(lr * 25 + mm) * PITCH + lh * 8]);
                acc[mm][0] = __builtin_amdgcn_mfma_f32_16x16x32_bf16(a, bfr[L0[mm]][0], acc[mm][0], 0, 0, 0);
                acc[mm][1] = __builtin_amdgcn_mfma_f32_16x16x32_bf16(a, bfr[L0[mm]][1], acc[mm][1], 0, 0, 0);
            }
        } else {                  // m 13..24, l in {3,4}
            bf16x8v bfr[2][2];
#pragma unroll
            for (int li = 0; li < 2; ++li)
#pragma unroll
                for (int of = 0; of < 2; ++of)
                    bfr[li][of] = *reinterpret_cast<const bf16x8v*>(
                        wb + (size_t)((li + 3) * 512 + ob + of * 16 + lr) * 512 + s * 32 + lh * 8);
            constexpr int L1[12] = {0,0,0,1,1,1,1,1,1,1,1,1};
#pragma unroll
            for (int mm = 0; mm < 12; ++mm) {
                const bf16x8v a = *reinterpret_cast<const bf16x8v*>(
                    &Asm[(lr * 25 + 13 + mm) * PITCH + lh * 8]);
                acc[mm][0] = __builtin_amdgcn_mfma_f32_16x16x32_bf16(a, bfr[L1[mm]][0], acc[mm][0], 0, 0, 0);
                acc[mm][1] = __builtin_amdgcn_mfma_f32_16x16x32_bf16(a, bfr[L1[mm]][1], acc[mm][1], 0, 0, 0);
            }
        }
    }

    // bias on the m=0 component only (held by mh==0 waves, mm==0)
    if (mh == 0) {
#pragma unroll
        for (int of = 0; of < 2; ++of) {
            float bv = bias[ob + of * 16 + lr];
#pragma unroll
            for (int r = 0; r < 4; ++r) acc[0][of][r] += bv;
        }
    }

    // ---- LDS-staged epilogue: 4 passes x 4 b-rows; stores = contiguous 12.8KB
    // float4 runs per row. ep write lanes stride 25 words (coprime 32) = clean.
    float* ep = reinterpret_cast<float*>(smem);
    constexpr int EPROW = 3208;   // 3200 + 8 pad
#pragma unroll 1
    for (int p = 0; p < 4; ++p) {
        __syncthreads();          // k-loop reads / prior pass reads done
        if (lh == p) {            // D rows = lh*4 + r -> global rows 4p..4p+3
            if (mh == 0) {
#pragma unroll
                for (int of = 0; of < 2; ++of) {
                    int cb = (oq * 32 + of * 16 + lr) * 25;
#pragma unroll
                    for (int mm = 0; mm < 13; ++mm)
#pragma unroll
                        for (int r = 0; r < 4; ++r)
                            ep[r * EPROW + cb + mm] = acc[mm][of][r];
                }
            } else {
#pragma unroll
                for (int of = 0; of < 2; ++of) {
                    int cb = (oq * 32 + of * 16 + lr) * 25 + 13;
#pragma unroll
                    for (int mm = 0; mm < 12; ++mm)
#pragma unroll
                        for (int r = 0; r < 4; ++r)
                            ep[r * EPROW + cb + mm] = acc[mm][of][r];
                }
            }
        }
        __syncthreads();
#pragma unroll 1
        for (int idx = tid; idx < 3200; idx += 512) {
            int rr = idx / 800, c4 = idx - rr * 800;
            floatx4 v = *reinterpret_cast<const floatx4*>(ep + rr * EPROW + c4 * 4);
            *reinterpret_cast<floatx4*>(
                out + (size_t)(b0 + p * 4 + rr) * ROW_F + o0 * 25 + c4 * 4) = v;
        }
    }
}

extern "C" void kernel_launch(void* const* d_in, const int* in_sizes, int n_in,
                              void* d_out, int out_size, void* d_ws, size_t ws_size,
                              hipStream_t stream) {
    const float* x    = (const float*)d_in[0];
    const float* w    = (const float*)d_in[1];
    const float* bias = (const float*)d_in[2];
    float* outp       = (float*)d_out;
    ushort_t* wb      = (ushort_t*)d_ws;    // 2.62 MB bf16 weights

    cvt_w_kernel<<<1280, 256, 0, stream>>>(w, wb);
    irrep_kernel<<<1024, 512, 0, stream>>>(x, wb, bias, outp);
}